// Round 4
// baseline (727.711 us; speedup 1.0000x reference)
//
#include <hip/hip_runtime.h>
#include <hip/hip_bf16.h>

typedef unsigned short u16;
typedef unsigned int   u32;
typedef __bf16 bf16x8 __attribute__((ext_vector_type(8)));
typedef float  f32x4  __attribute__((ext_vector_type(4)));

static constexpr int B_ = 4, T_ = 2048, D_ = 2048, NH_ = 8, NKV_ = 4, HD_ = 256;
static constexpr int QKVC = (NH_ + 2 * NKV_) * HD_;   // 4096
static constexpr int ENC_C = NH_ * HD_;               // 2048

__device__ __forceinline__ u16 f2b(float f) {
  u32 x = __float_as_uint(f);
  return (u16)((x + 0x7fffu + ((x >> 16) & 1u)) >> 16);
}
__device__ __forceinline__ float b2f(u16 u) { return __uint_as_float(((u32)u) << 16); }

__device__ __forceinline__ void gload_lds16(const void* g, void* l) {
  __builtin_amdgcn_global_load_lds((const __attribute__((address_space(1))) void*)g,
                                   (__attribute__((address_space(3))) void*)l, 16, 0, 0);
}

// ---------------- fp32 -> bf16 elementwise ----------------
__global__ void cvt_f32_bf16(const float* __restrict__ in, u16* __restrict__ out, int n) {
  for (size_t i = ((size_t)blockIdx.x * 256 + threadIdx.x) * 8; i < (size_t)n;
       i += (size_t)gridDim.x * 256 * 8) {
    float4 a = *(const float4*)(in + i);
    float4 b = *(const float4*)(in + i + 4);
    u16 t[8] = {f2b(a.x), f2b(a.y), f2b(a.z), f2b(a.w), f2b(b.x), f2b(b.y), f2b(b.z), f2b(b.w)};
    *(uint4*)(out + i) = *(const uint4*)t;
  }
}

// ---------------- fp32 (R x C) -> bf16 transposed (C x R) ----------------
__global__ void transpose_cvt(const float* __restrict__ src, u16* __restrict__ dst, int R, int C) {
  __shared__ u16 tl[64][72];
  const int c0 = blockIdx.x << 6, r0 = blockIdx.y << 6;
  const int tid = threadIdx.x;
  const int lr = tid >> 2, lc = (tid & 3) << 4;
  const float* p = src + (size_t)(r0 + lr) * C + c0 + lc;
#pragma unroll
  for (int j = 0; j < 16; j += 4) {
    float4 v = *(const float4*)(p + j);
    tl[lr][lc + j + 0] = f2b(v.x);
    tl[lr][lc + j + 1] = f2b(v.y);
    tl[lr][lc + j + 2] = f2b(v.z);
    tl[lr][lc + j + 3] = f2b(v.w);
  }
  __syncthreads();
  u16 tmp[16];
#pragma unroll
  for (int j = 0; j < 16; j++) tmp[j] = tl[lc + j][lr];
  u16* q = dst + (size_t)(c0 + lr) * R + r0 + lc;
  *(uint4*)q = *(const uint4*)tmp;
  *(uint4*)(q + 8) = *(const uint4*)(tmp + 8);
}

// ---------------- bf16 V slice of qkv -> VT (b,kv,HD,T) ----------------
__global__ void vt_build(const u16* __restrict__ qkv, u16* __restrict__ vt) {
  __shared__ u16 tl[64][72];
  const int t0 = blockIdx.x << 6, d0 = blockIdx.y << 6, z = blockIdx.z; // z = b*4+kv
  const int tid = threadIdx.x;
  const int lr = tid >> 2, lc = (tid & 3) << 4;
  const u16* p = qkv + (size_t)((z >> 2) * T_ + t0 + lr) * QKVC + (NH_ + NKV_) * HD_ +
                 (z & 3) * HD_ + d0 + lc;
#pragma unroll
  for (int j = 0; j < 16; j++) tl[lr][lc + j] = p[j];  // tl[t_local][d_local]
  __syncthreads();
  u16 tmp[16];
#pragma unroll
  for (int j = 0; j < 16; j++) tmp[j] = tl[lc + j][lr];
  u16* q = vt + ((size_t)z * HD_ + d0 + lr) * T_ + t0 + lc;
  *(uint4*)q = *(const uint4*)tmp;
  *(uint4*)(q + 8) = *(const uint4*)(tmp + 8);
}

// ---------------- RoPE in-place, vectorized (uint4 = 8 bf16 per access) ----------------
__global__ void rope_inplace(u16* __restrict__ qkv, const int* __restrict__ positions) {
  const int row = blockIdx.x;  // b*T + t
  const int t = threadIdx.x;
  if (t >= 192) return;
  const float pos = (float)positions[row];
  const int head = t >> 4, i8 = (t & 15) << 3;
  u16* p1 = qkv + (size_t)row * QKVC + head * HD_ + i8;
  u16* p2 = p1 + 128;
  uint4 a = *(const uint4*)p1, b = *(const uint4*)p2;
  u16 o1[8], o2[8];
#pragma unroll
  for (int j = 0; j < 8; j++) {
    const int i = i8 + j;
    const float inv = exp2f(-(float)i * 0.10381025296522975f);  // log2(10000)/128
    float s, c;
    __sincosf(pos * inv, &s, &c);
    const float x1 = b2f(((const u16*)&a)[j]), x2 = b2f(((const u16*)&b)[j]);
    o1[j] = f2b(x1 * c - x2 * s);
    o2[j] = f2b(x2 * c + x1 * s);
  }
  *(uint4*)p1 = *(const uint4*)o1;
  *(uint4*)p2 = *(const uint4*)o2;
}

// ---------------- GEMM, counted-vmcnt pipeline ----------------
// C(MxN) = A(MxK) * Bt(NxK)^T, bf16 in, fp32 acc. BM=BN=256, BK=32.
// 4 rotating LDS buffers, prefetch distance 2 -> steady wait = vmcnt(4), never 0.
// 8 waves (2M x 4N), per-wave 128x64 out, acc[8][4] f32x4.
// LDS row-major [256][32]: 32-el rows spread bank quads uniformly -> conflict-free.
template <bool OUT_F32>
__global__ __launch_bounds__(512, 2) void gemm8p(const u16* __restrict__ A,
                                                 const u16* __restrict__ Bt,
                                                 void* __restrict__ Cp, int M, int N, int K) {
  __shared__ __align__(16) u16 Al[4][8192];
  __shared__ __align__(16) u16 Bl[4][8192];
  const int tid = threadIdx.x, wid = tid >> 6, l = tid & 63;
  const int wm = wid >> 2, wn = wid & 3;
  const int lr = l & 15, khi = l >> 4;

  // XCD-bijective swizzle (gridDim.x % 8 == 0 for both GEMMs)
  const int nwg = gridDim.x;
  const int wg = (blockIdx.x & 7) * (nwg >> 3) + (blockIdx.x >> 3);
  const int nbx = N >> 8;
  const size_t bm = (size_t)(wg / nbx) << 8, bn = (size_t)(wg % nbx) << 8;

  const int nt = K >> 5;
  f32x4 acc[8][4] = {};

  const int srow = tid >> 2, scol = (tid & 3) << 3;  // stage: thread covers 2 slots
  auto stage = [&](int buf, int kt) {
    const size_t k0 = (size_t)kt << 5;
    gload_lds16(A + (bm + srow) * K + k0 + scol, &Al[buf][tid * 8]);
    gload_lds16(A + (bm + 128 + srow) * K + k0 + scol, &Al[buf][4096 + tid * 8]);
    gload_lds16(Bt + (bn + srow) * K + k0 + scol, &Bl[buf][tid * 8]);
    gload_lds16(Bt + (bn + 128 + srow) * K + k0 + scol, &Bl[buf][4096 + tid * 8]);
  };

  stage(0, 0);
  stage(1, 1);

  for (int t = 0; t < nt; ++t) {
    const int buf = t & 3;
    if (t < nt - 1) {
      asm volatile("s_waitcnt vmcnt(4)" ::: "memory");
    } else {
      asm volatile("s_waitcnt vmcnt(0)" ::: "memory");
    }
    __builtin_amdgcn_sched_barrier(0);
    __builtin_amdgcn_s_barrier();
    __builtin_amdgcn_sched_barrier(0);

    const u16* Ab = Al[buf];
    const u16* Bb = Bl[buf];
    const bool pf = (t + 2 < nt);

    // ---- phase A: m-frags 0..3 ----
    if (pf) {
      const size_t k0 = (size_t)(t + 2) << 5;
      const int nb = (t + 2) & 3;
      gload_lds16(A + (bm + srow) * K + k0 + scol, &Al[nb][tid * 8]);
      gload_lds16(A + (bm + 128 + srow) * K + k0 + scol, &Al[nb][4096 + tid * 8]);
    }
    bf16x8 bF[4], aF[4];
#pragma unroll
    for (int nf = 0; nf < 4; nf++)
      bF[nf] = *(const bf16x8*)&Bb[((wn << 6) + (nf << 4) + lr) * 32 + (khi << 3)];
#pragma unroll
    for (int mf = 0; mf < 4; mf++)
      aF[mf] = *(const bf16x8*)&Ab[((wm << 7) + (mf << 4) + lr) * 32 + (khi << 3)];
    __builtin_amdgcn_s_setprio(1);
#pragma unroll
    for (int mf = 0; mf < 4; mf++)
#pragma unroll
      for (int nf = 0; nf < 4; nf++)
        acc[mf][nf] = __builtin_amdgcn_mfma_f32_16x16x32_bf16(aF[mf], bF[nf], acc[mf][nf], 0, 0, 0);
    __builtin_amdgcn_s_setprio(0);

    // ---- phase B: m-frags 4..7 (bF reused) ----
    if (pf) {
      const size_t k0 = (size_t)(t + 2) << 5;
      const int nb = (t + 2) & 3;
      gload_lds16(Bt + (bn + srow) * K + k0 + scol, &Bl[nb][tid * 8]);
      gload_lds16(Bt + (bn + 128 + srow) * K + k0 + scol, &Bl[nb][4096 + tid * 8]);
    }
#pragma unroll
    for (int mf = 0; mf < 4; mf++)
      aF[mf] = *(const bf16x8*)&Ab[((wm << 7) + ((mf + 4) << 4) + lr) * 32 + (khi << 3)];
    __builtin_amdgcn_s_setprio(1);
#pragma unroll
    for (int mf = 0; mf < 4; mf++)
#pragma unroll
      for (int nf = 0; nf < 4; nf++)
        acc[mf + 4][nf] = __builtin_amdgcn_mfma_f32_16x16x32_bf16(aF[mf], bF[nf], acc[mf + 4][nf], 0, 0, 0);
    __builtin_amdgcn_s_setprio(0);
  }

#pragma unroll
  for (int mf = 0; mf < 8; mf++) {
#pragma unroll
    for (int j = 0; j < 4; j++) {
      const size_t row = bm + (wm << 7) + (mf << 4) + (khi << 2) + j;
#pragma unroll
      for (int nf = 0; nf < 4; nf++) {
        const size_t col = bn + (wn << 6) + (nf << 4) + lr;
        if constexpr (OUT_F32)
          ((float*)Cp)[row * N + col] = acc[mf][nf][j];
        else
          ((u16*)Cp)[row * N + col] = f2b(acc[mf][nf][j]);
      }
    }
  }
}

// ---------------- fused causal attention ----------------
// Swapped QK^T (S^T = K x Q) with sigma-permuted K rows; fixed softmax max
// (soft-cap bounds logits) -> in-register P, no shuffles in the loop.
// K/V tiles staged to LDS in *fragment order* via global_load_lds: every
// ds_read_b128 is a contiguous 1KB wave read -> conflict-free by construction.
// 8 waves x 32 q rows; block owns q-chunks qb and 15-qb -> uniform work.
// Double-buffered LDS (128KB), 1 barrier per tile. setprio around MFMA (T5).
__global__ __launch_bounds__(512, 2) void attn_kernel(const u16* __restrict__ qkv,
                                                      const u16* __restrict__ VT,
                                                      u16* __restrict__ enc) {
  __shared__ __align__(16) u16 Kl[2][16384];
  __shared__ __align__(16) u16 Vl[2][16384];
  const int tid = threadIdx.x, w = tid >> 6, l = tid & 63;
  const int lr = l & 15, khi = l >> 4;
  const int id = blockIdx.x;
  const int xcd = id & 7, slot = id >> 3;
  const int group = xcd + ((slot >> 4) << 3), sub = slot & 15;
  const int b = group >> 2, kv = group & 3;
  const int h = (kv << 1) + (sub & 1), qb = sub >> 1;   // qb in 0..7
  const int chunk = (w < 4) ? qb : (15 - qb);
  const int qw = (chunk << 7) + ((w & 3) << 5);         // wave's 32-row q base
  const int qmax = qw + 31;
  const int nst = 32 - 2 * qb;                          // tiles for the longer chunk

  bf16x8 qf[2][8];
#pragma unroll
  for (int qg = 0; qg < 2; qg++) {
    const u16* qrow = qkv + (size_t)(b * T_ + qw + qg * 16 + lr) * QKVC + h * HD_ + khi * 8;
#pragma unroll
    for (int kk = 0; kk < 8; kk++) qf[qg][kk] = *(const bf16x8*)(qrow + kk * 32);
  }

  int offK[4], offV[4];
#pragma unroll
  for (int j = 0; j < 4; j++) {
    const int gg = j * 8 + w;
    const int sg = gg >> 3, kk = gg & 7;
    const int srow = ((sg >> 1) << 5) + ((sg & 1) << 2) + ((lr >> 2) << 3) + (lr & 3);
    offK[j] = srow * QKVC + kk * 32 + khi * 8;
    const int ks = gg >> 4, nf = gg & 15;
    offV[j] = ((nf << 4) + lr) * T_ + (ks << 5) + khi * 8;
  }
  const u16* Kp = qkv + (size_t)b * T_ * QKVC + NH_ * HD_ + kv * HD_;
  const u16* Vp = VT + (size_t)(b * NKV_ + kv) * HD_ * T_;

  f32x4 opv[2][16] = {};
  float lsum[2] = {0.f, 0.f};

  auto stage = [&](int bf, int st) {
    const u16* kp = Kp + (size_t)(st << 6) * QKVC;
    const u16* vp = Vp + (st << 6);
#pragma unroll
    for (int j = 0; j < 4; j++) {
      gload_lds16(kp + offK[j], &Kl[bf][(j * 8 + w) * 512]);
      gload_lds16(vp + offV[j], &Vl[bf][(j * 8 + w) * 512]);
    }
  };

  stage(0, 0);
  __syncthreads();
  int buf = 0;
  for (int st = 0; st < nst; ++st) {
    if (st + 1 < nst) stage(buf ^ 1, st + 1);
    const int s0 = st << 6;
    if (s0 <= qmax) {
      const u16* Kb = Kl[buf];
      const u16* Vb = Vl[buf];
#pragma unroll
      for (int ks = 0; ks < 2; ks++) {
        f32x4 pst[2][2] = {};
        __builtin_amdgcn_s_setprio(1);
#pragma unroll
        for (int sgh = 0; sgh < 2; sgh++) {
          const int gb = ((ks << 1) + sgh) * 8;
#pragma unroll
          for (int kk = 0; kk < 8; kk++) {
            bf16x8 kf = *(const bf16x8*)&Kb[(gb + kk) * 512 + l * 8];
            pst[0][sgh] = __builtin_amdgcn_mfma_f32_16x16x32_bf16(kf, qf[0][kk], pst[0][sgh], 0, 0, 0);
            pst[1][sgh] = __builtin_amdgcn_mfma_f32_16x16x32_bf16(kf, qf[1][kk], pst[1][sgh], 0, 0, 0);
          }
        }
        __builtin_amdgcn_s_setprio(0);
        union { u32 u[4]; bf16x8 v; } ap[2];
#pragma unroll
        for (int qg = 0; qg < 2; qg++) {
          const int tq = qw + qg * 16 + lr;
#pragma unroll
          for (int sgh = 0; sgh < 2; sgh++) {
#pragma unroll
            for (int j = 0; j < 4; j++) {
              const int s = s0 + ks * 32 + khi * 8 + sgh * 4 + j;
              const float e2 = __expf(pst[qg][sgh][j] * 0.04f);
              float p = __expf(-6.25f * __builtin_amdgcn_rcpf(e2 + 1.f));
              p = (s <= tq) ? p : 0.f;
              pst[qg][sgh][j] = p;
              lsum[qg] += p;
            }
          }
          ap[qg].u[0] = __builtin_amdgcn_perm(__float_as_uint(pst[qg][0][1]),
                                              __float_as_uint(pst[qg][0][0]), 0x07060302u);
          ap[qg].u[1] = __builtin_amdgcn_perm(__float_as_uint(pst[qg][0][3]),
                                              __float_as_uint(pst[qg][0][2]), 0x07060302u);
          ap[qg].u[2] = __builtin_amdgcn_perm(__float_as_uint(pst[qg][1][1]),
                                              __float_as_uint(pst[qg][1][0]), 0x07060302u);
          ap[qg].u[3] = __builtin_amdgcn_perm(__float_as_uint(pst[qg][1][3]),
                                              __float_as_uint(pst[qg][1][2]), 0x07060302u);
        }
        __builtin_amdgcn_s_setprio(1);
#pragma unroll
        for (int nf = 0; nf < 16; nf++) {
          bf16x8 bv = *(const bf16x8*)&Vb[((ks << 4) + nf) * 512 + l * 8];
          opv[0][nf] = __builtin_amdgcn_mfma_f32_16x16x32_bf16(ap[0].v, bv, opv[0][nf], 0, 0, 0);
          opv[1][nf] = __builtin_amdgcn_mfma_f32_16x16x32_bf16(ap[1].v, bv, opv[1][nf], 0, 0, 0);
        }
        __builtin_amdgcn_s_setprio(0);
      }
    }
    __syncthreads();
    buf ^= 1;
  }

#pragma unroll
  for (int qg = 0; qg < 2; qg++) {
    float s = lsum[qg];
    s += __shfl_xor(s, 16);
    s += __shfl_xor(s, 32);
    const float rinv = 1.f / s;
#pragma unroll
    for (int j = 0; j < 4; j++) {
      const float rj = __shfl(rinv, (khi << 2) + j);
      const size_t row = (size_t)(b * T_ + qw + qg * 16 + (khi << 2) + j) * ENC_C + h * HD_ + lr;
#pragma unroll
      for (int nf = 0; nf < 16; nf++) enc[row + (nf << 4)] = f2b(opv[qg][nf][j] * rj);
    }
  }
}

// ---------------- launcher ----------------
extern "C" void kernel_launch(void* const* d_in, const int* in_sizes, int n_in,
                              void* d_out, int out_size, void* d_ws, size_t ws_size,
                              hipStream_t stream) {
  const float* x = (const float*)d_in[0];
  const int* positions = (const int*)d_in[1];
  // d_in[2] attn_mask: causal tril by construction -> handled analytically
  const float* w_qkv = (const float*)d_in[3];
  const float* w_out = (const float*)d_in[4];
  float* out = (float*)d_out;

  char* ws = (char*)d_ws;
  u16* X16 = (u16*)(ws + 0);               // 32 MB : x bf16 (8192 x 2048)
  u16* WQT = (u16*)(ws + 33554432);        // 16 MB : w_qkv^T bf16 (4096 x 2048)
  u16* WOT = (u16*)(ws + 50331648);        //  8 MB : w_out^T bf16 (2048 x 2048)
  u16* QKV = (u16*)(ws + 58720256);        // 64 MB : qkv bf16 (8192 x 4096)
  u16* VT  = (u16*)(ws + 125829120);       // 16 MB : V^T bf16 (b,kv,HD,T)
  u16* ENC = X16;                          // alias (x bf16 dead after gemm1)

  cvt_f32_bf16<<<2048, 256, 0, stream>>>(x, X16, B_ * T_ * D_);
  {
    dim3 g(QKVC / 64, D_ / 64);
    transpose_cvt<<<g, 256, 0, stream>>>(w_qkv, WQT, D_, QKVC);
  }
  {
    dim3 g(D_ / 64, ENC_C / 64);
    transpose_cvt<<<g, 256, 0, stream>>>(w_out, WOT, ENC_C, D_);
  }
  gemm8p<false><<<(B_ * T_ / 256) * (QKVC / 256), 512, 0, stream>>>(X16, WQT, QKV,
                                                                    B_ * T_, QKVC, D_);
  rope_inplace<<<B_ * T_, 256, 0, stream>>>(QKV, positions);
  {
    dim3 g(T_ / 64, HD_ / 64, B_ * NKV_);
    vt_build<<<g, 256, 0, stream>>>(QKV, VT);
  }
  attn_kernel<<<256, 512, 0, stream>>>(QKV, VT, ENC);
  gemm8p<true><<<(B_ * T_ / 256) * (D_ / 256), 512, 0, stream>>>(ENC, WOT, out,
                                                                 B_ * T_, D_, ENC_C);
}

// Round 5
// 613.764 us; speedup vs baseline: 1.1857x; 1.1857x over previous
//
#include <hip/hip_runtime.h>
#include <hip/hip_bf16.h>

typedef unsigned short u16;
typedef unsigned int   u32;
typedef __bf16 bf16x8 __attribute__((ext_vector_type(8)));
typedef float  f32x4  __attribute__((ext_vector_type(4)));

static constexpr int B_ = 4, T_ = 2048, D_ = 2048, NH_ = 8, NKV_ = 4, HD_ = 256;
static constexpr int QKVC = (NH_ + 2 * NKV_) * HD_;   // 4096
static constexpr int ENC_C = NH_ * HD_;               // 2048

__device__ __forceinline__ u16 f2b(float f) {
  u32 x = __float_as_uint(f);
  return (u16)((x + 0x7fffu + ((x >> 16) & 1u)) >> 16);
}
__device__ __forceinline__ float b2f(u16 u) { return __uint_as_float(((u32)u) << 16); }

__device__ __forceinline__ void gload_lds16(const void* g, void* l) {
  __builtin_amdgcn_global_load_lds((const __attribute__((address_space(1))) void*)g,
                                   (__attribute__((address_space(3))) void*)l, 16, 0, 0);
}

// ---------------- fp32 -> bf16 elementwise ----------------
__global__ void cvt_f32_bf16(const float* __restrict__ in, u16* __restrict__ out, int n) {
  for (size_t i = ((size_t)blockIdx.x * 256 + threadIdx.x) * 8; i < (size_t)n;
       i += (size_t)gridDim.x * 256 * 8) {
    float4 a = *(const float4*)(in + i);
    float4 b = *(const float4*)(in + i + 4);
    u16 t[8] = {f2b(a.x), f2b(a.y), f2b(a.z), f2b(a.w), f2b(b.x), f2b(b.y), f2b(b.z), f2b(b.w)};
    *(uint4*)(out + i) = *(const uint4*)t;
  }
}

// ---------------- fp32 (R x C) -> bf16 transposed (C x R) ----------------
__global__ void transpose_cvt(const float* __restrict__ src, u16* __restrict__ dst, int R, int C) {
  __shared__ u16 tl[64][72];
  const int c0 = blockIdx.x << 6, r0 = blockIdx.y << 6;
  const int tid = threadIdx.x;
  const int lr = tid >> 2, lc = (tid & 3) << 4;
  const float* p = src + (size_t)(r0 + lr) * C + c0 + lc;
#pragma unroll
  for (int j = 0; j < 16; j += 4) {
    float4 v = *(const float4*)(p + j);
    tl[lr][lc + j + 0] = f2b(v.x);
    tl[lr][lc + j + 1] = f2b(v.y);
    tl[lr][lc + j + 2] = f2b(v.z);
    tl[lr][lc + j + 3] = f2b(v.w);
  }
  __syncthreads();
  u16 tmp[16];
#pragma unroll
  for (int j = 0; j < 16; j++) tmp[j] = tl[lc + j][lr];
  u16* q = dst + (size_t)(c0 + lr) * R + r0 + lc;
  *(uint4*)q = *(const uint4*)tmp;
  *(uint4*)(q + 8) = *(const uint4*)(tmp + 8);
}

// ---------------- bf16 V slice of qkv -> VT (b,kv,HD,T) ----------------
__global__ void vt_build(const u16* __restrict__ qkv, u16* __restrict__ vt) {
  __shared__ u16 tl[64][72];
  const int t0 = blockIdx.x << 6, d0 = blockIdx.y << 6, z = blockIdx.z; // z = b*4+kv
  const int tid = threadIdx.x;
  const int lr = tid >> 2, lc = (tid & 3) << 4;
  const u16* p = qkv + (size_t)((z >> 2) * T_ + t0 + lr) * QKVC + (NH_ + NKV_) * HD_ +
                 (z & 3) * HD_ + d0 + lc;
#pragma unroll
  for (int j = 0; j < 16; j++) tl[lr][lc + j] = p[j];  // tl[t_local][d_local]
  __syncthreads();
  u16 tmp[16];
#pragma unroll
  for (int j = 0; j < 16; j++) tmp[j] = tl[lc + j][lr];
  u16* q = vt + ((size_t)z * HD_ + d0 + lr) * T_ + t0 + lc;
  *(uint4*)q = *(const uint4*)tmp;
  *(uint4*)(q + 8) = *(const uint4*)(tmp + 8);
}

// ---------------- RoPE in-place, vectorized (uint4 = 8 bf16 per access) ----------------
__global__ void rope_inplace(u16* __restrict__ qkv, const int* __restrict__ positions) {
  const int row = blockIdx.x;  // b*T + t
  const int t = threadIdx.x;
  if (t >= 192) return;
  const float pos = (float)positions[row];
  const int head = t >> 4, i8 = (t & 15) << 3;
  u16* p1 = qkv + (size_t)row * QKVC + head * HD_ + i8;
  u16* p2 = p1 + 128;
  uint4 a = *(const uint4*)p1, b = *(const uint4*)p2;
  u16 o1[8], o2[8];
#pragma unroll
  for (int j = 0; j < 8; j++) {
    const int i = i8 + j;
    const float inv = exp2f(-(float)i * 0.10381025296522975f);  // log2(10000)/128
    float s, c;
    __sincosf(pos * inv, &s, &c);
    const float x1 = b2f(((const u16*)&a)[j]), x2 = b2f(((const u16*)&b)[j]);
    o1[j] = f2b(x1 * c - x2 * s);
    o2[j] = f2b(x2 * c + x1 * s);
  }
  *(uint4*)p1 = *(const uint4*)o1;
  *(uint4*)p2 = *(const uint4*)o2;
}

// ---------------- GEMM, counted-vmcnt pipeline ----------------
// C(MxN) = A(MxK) * Bt(NxK)^T, bf16 in, fp32 acc. BM=BN=256, BK=32.
// 4 rotating LDS buffers, prefetch distance 2 -> steady wait = vmcnt(4), never 0.
// 8 waves (2M x 4N), per-wave 128x64 out, acc[8][4] f32x4.
// LDS [256 rows][4 slots of 16B], slot XOR-swizzled by (row>>1)&3:
// frag read addr = r*64B + (khi^((r>>1)&3))*16B -> all 8 bank-groups over r=0..7,
// 2-way over 16 rows (free). Stage pre-swizzles the GLOBAL source column (G21).
template <bool OUT_F32>
__global__ __launch_bounds__(512, 2) void gemm8p(const u16* __restrict__ A,
                                                 const u16* __restrict__ Bt,
                                                 void* __restrict__ Cp, int M, int N, int K) {
  __shared__ __align__(16) u16 Al[4][8192];
  __shared__ __align__(16) u16 Bl[4][8192];
  const int tid = threadIdx.x, wid = tid >> 6, l = tid & 63;
  const int wm = wid >> 2, wn = wid & 3;
  const int lr = l & 15, khi = l >> 4;

  // XCD-bijective swizzle (gridDim.x % 8 == 0 for both GEMMs)
  const int nwg = gridDim.x;
  const int wg = (blockIdx.x & 7) * (nwg >> 3) + (blockIdx.x >> 3);
  const int nbx = N >> 8;
  const size_t bm = (size_t)(wg / nbx) << 8, bn = (size_t)(wg % nbx) << 8;

  const int nt = K >> 5;
  f32x4 acc[8][4] = {};

  const int srow = tid >> 2;                                        // 0..127
  const int scol = (((tid & 3) ^ ((srow >> 1) & 3)) << 3);          // swizzled global col
  auto stage = [&](int buf, int kt) {
    const size_t k0 = (size_t)kt << 5;
    gload_lds16(A + (bm + srow) * K + k0 + scol, &Al[buf][tid * 8]);
    gload_lds16(A + (bm + 128 + srow) * K + k0 + scol, &Al[buf][4096 + tid * 8]);
    gload_lds16(Bt + (bn + srow) * K + k0 + scol, &Bl[buf][tid * 8]);
    gload_lds16(Bt + (bn + 128 + srow) * K + k0 + scol, &Bl[buf][4096 + tid * 8]);
  };

  stage(0, 0);
  stage(1, 1);

  for (int t = 0; t < nt; ++t) {
    const int buf = t & 3;
    if (t < nt - 1) {
      asm volatile("s_waitcnt vmcnt(4)" ::: "memory");
    } else {
      asm volatile("s_waitcnt vmcnt(0)" ::: "memory");
    }
    __builtin_amdgcn_sched_barrier(0);
    __builtin_amdgcn_s_barrier();
    __builtin_amdgcn_sched_barrier(0);

    const u16* Ab = Al[buf];
    const u16* Bb = Bl[buf];
    const bool pf = (t + 2 < nt);

    // ---- phase A: m-frags 0..3 ----
    if (pf) {
      const size_t k0 = (size_t)(t + 2) << 5;
      const int nb = (t + 2) & 3;
      gload_lds16(A + (bm + srow) * K + k0 + scol, &Al[nb][tid * 8]);
      gload_lds16(A + (bm + 128 + srow) * K + k0 + scol, &Al[nb][4096 + tid * 8]);
    }
    bf16x8 bF[4], aF[4];
#pragma unroll
    for (int nf = 0; nf < 4; nf++) {
      const int c = (wn << 6) + (nf << 4) + lr;
      bF[nf] = *(const bf16x8*)&Bb[c * 32 + ((khi ^ ((c >> 1) & 3)) << 3)];
    }
#pragma unroll
    for (int mf = 0; mf < 4; mf++) {
      const int r = (wm << 7) + (mf << 4) + lr;
      aF[mf] = *(const bf16x8*)&Ab[r * 32 + ((khi ^ ((r >> 1) & 3)) << 3)];
    }
    __builtin_amdgcn_s_setprio(1);
#pragma unroll
    for (int mf = 0; mf < 4; mf++)
#pragma unroll
      for (int nf = 0; nf < 4; nf++)
        acc[mf][nf] = __builtin_amdgcn_mfma_f32_16x16x32_bf16(aF[mf], bF[nf], acc[mf][nf], 0, 0, 0);
    __builtin_amdgcn_s_setprio(0);

    // ---- phase B: m-frags 4..7 (bF reused) ----
    if (pf) {
      const size_t k0 = (size_t)(t + 2) << 5;
      const int nb = (t + 2) & 3;
      gload_lds16(Bt + (bn + srow) * K + k0 + scol, &Bl[nb][tid * 8]);
      gload_lds16(Bt + (bn + 128 + srow) * K + k0 + scol, &Bl[nb][4096 + tid * 8]);
    }
#pragma unroll
    for (int mf = 0; mf < 4; mf++) {
      const int r = (wm << 7) + ((mf + 4) << 4) + lr;
      aF[mf] = *(const bf16x8*)&Ab[r * 32 + ((khi ^ ((r >> 1) & 3)) << 3)];
    }
    __builtin_amdgcn_s_setprio(1);
#pragma unroll
    for (int mf = 0; mf < 4; mf++)
#pragma unroll
      for (int nf = 0; nf < 4; nf++)
        acc[mf + 4][nf] = __builtin_amdgcn_mfma_f32_16x16x32_bf16(aF[mf], bF[nf], acc[mf + 4][nf], 0, 0, 0);
    __builtin_amdgcn_s_setprio(0);
  }

#pragma unroll
  for (int mf = 0; mf < 8; mf++) {
#pragma unroll
    for (int j = 0; j < 4; j++) {
      const size_t row = bm + (wm << 7) + (mf << 4) + (khi << 2) + j;
#pragma unroll
      for (int nf = 0; nf < 4; nf++) {
        const size_t col = bn + (wn << 6) + (nf << 4) + lr;
        if constexpr (OUT_F32)
          ((float*)Cp)[row * N + col] = acc[mf][nf][j];
        else
          ((u16*)Cp)[row * N + col] = f2b(acc[mf][nf][j]);
      }
    }
  }
}

// ---------------- fused causal attention (r3-exact: NO setprio) ----------------
// Swapped QK^T (S^T = K x Q) with sigma-permuted K rows; fixed softmax max
// (soft-cap bounds logits) -> in-register P, no shuffles in the loop.
// K/V tiles staged to LDS in *fragment order* via global_load_lds: every
// ds_read_b128 is a contiguous 1KB wave read -> conflict-free by construction.
// 8 waves x 32 q rows; block owns q-chunks qb and 15-qb -> uniform work.
// Double-buffered LDS (128KB), 1 barrier per tile.
__global__ __launch_bounds__(512, 2) void attn_kernel(const u16* __restrict__ qkv,
                                                      const u16* __restrict__ VT,
                                                      u16* __restrict__ enc) {
  __shared__ __align__(16) u16 Kl[2][16384];
  __shared__ __align__(16) u16 Vl[2][16384];
  const int tid = threadIdx.x, w = tid >> 6, l = tid & 63;
  const int lr = l & 15, khi = l >> 4;
  const int id = blockIdx.x;
  const int xcd = id & 7, slot = id >> 3;
  const int group = xcd + ((slot >> 4) << 3), sub = slot & 15;
  const int b = group >> 2, kv = group & 3;
  const int h = (kv << 1) + (sub & 1), qb = sub >> 1;   // qb in 0..7
  const int chunk = (w < 4) ? qb : (15 - qb);
  const int qw = (chunk << 7) + ((w & 3) << 5);         // wave's 32-row q base
  const int qmax = qw + 31;
  const int nst = 32 - 2 * qb;                          // tiles for the longer chunk

  bf16x8 qf[2][8];
#pragma unroll
  for (int qg = 0; qg < 2; qg++) {
    const u16* qrow = qkv + (size_t)(b * T_ + qw + qg * 16 + lr) * QKVC + h * HD_ + khi * 8;
#pragma unroll
    for (int kk = 0; kk < 8; kk++) qf[qg][kk] = *(const bf16x8*)(qrow + kk * 32);
  }

  int offK[4], offV[4];
#pragma unroll
  for (int j = 0; j < 4; j++) {
    const int gg = j * 8 + w;
    const int sg = gg >> 3, kk = gg & 7;
    const int srow = ((sg >> 1) << 5) + ((sg & 1) << 2) + ((lr >> 2) << 3) + (lr & 3);
    offK[j] = srow * QKVC + kk * 32 + khi * 8;
    const int ks = gg >> 4, nf = gg & 15;
    offV[j] = ((nf << 4) + lr) * T_ + (ks << 5) + khi * 8;
  }
  const u16* Kp = qkv + (size_t)b * T_ * QKVC + NH_ * HD_ + kv * HD_;
  const u16* Vp = VT + (size_t)(b * NKV_ + kv) * HD_ * T_;

  f32x4 opv[2][16] = {};
  float lsum[2] = {0.f, 0.f};

  auto stage = [&](int bf, int st) {
    const u16* kp = Kp + (size_t)(st << 6) * QKVC;
    const u16* vp = Vp + (st << 6);
#pragma unroll
    for (int j = 0; j < 4; j++) {
      gload_lds16(kp + offK[j], &Kl[bf][(j * 8 + w) * 512]);
      gload_lds16(vp + offV[j], &Vl[bf][(j * 8 + w) * 512]);
    }
  };

  stage(0, 0);
  __syncthreads();
  int buf = 0;
  for (int st = 0; st < nst; ++st) {
    if (st + 1 < nst) stage(buf ^ 1, st + 1);
    const int s0 = st << 6;
    if (s0 <= qmax) {  // wave-uniform skip of fully-masked tiles
      const u16* Kb = Kl[buf];
      const u16* Vb = Vl[buf];
#pragma unroll
      for (int ks = 0; ks < 2; ks++) {
        f32x4 pst[2][2] = {};
#pragma unroll
        for (int sgh = 0; sgh < 2; sgh++) {
          const int gb = ((ks << 1) + sgh) * 8;
#pragma unroll
          for (int kk = 0; kk < 8; kk++) {
            bf16x8 kf = *(const bf16x8*)&Kb[(gb + kk) * 512 + l * 8];
            pst[0][sgh] = __builtin_amdgcn_mfma_f32_16x16x32_bf16(kf, qf[0][kk], pst[0][sgh], 0, 0, 0);
            pst[1][sgh] = __builtin_amdgcn_mfma_f32_16x16x32_bf16(kf, qf[1][kk], pst[1][sgh], 0, 0, 0);
          }
        }
        // softcap + mask + fixed-max exp + pack to bf16 A-frags
        union { u32 u[4]; bf16x8 v; } ap[2];
#pragma unroll
        for (int qg = 0; qg < 2; qg++) {
          const int tq = qw + qg * 16 + lr;
#pragma unroll
          for (int sgh = 0; sgh < 2; sgh++) {
#pragma unroll
            for (int j = 0; j < 4; j++) {
              const int s = s0 + ks * 32 + khi * 8 + sgh * 4 + j;
              const float e2 = __expf(pst[qg][sgh][j] * 0.04f);
              float p = __expf(-6.25f * __builtin_amdgcn_rcpf(e2 + 1.f));
              p = (s <= tq) ? p : 0.f;
              pst[qg][sgh][j] = p;
              lsum[qg] += p;
            }
          }
          ap[qg].u[0] = __builtin_amdgcn_perm(__float_as_uint(pst[qg][0][1]),
                                              __float_as_uint(pst[qg][0][0]), 0x07060302u);
          ap[qg].u[1] = __builtin_amdgcn_perm(__float_as_uint(pst[qg][0][3]),
                                              __float_as_uint(pst[qg][0][2]), 0x07060302u);
          ap[qg].u[2] = __builtin_amdgcn_perm(__float_as_uint(pst[qg][1][1]),
                                              __float_as_uint(pst[qg][1][0]), 0x07060302u);
          ap[qg].u[3] = __builtin_amdgcn_perm(__float_as_uint(pst[qg][1][3]),
                                              __float_as_uint(pst[qg][1][2]), 0x07060302u);
        }
        // PV: each V-frag feeds both q-groups
#pragma unroll
        for (int nf = 0; nf < 16; nf++) {
          bf16x8 bv = *(const bf16x8*)&Vb[((ks << 4) + nf) * 512 + l * 8];
          opv[0][nf] = __builtin_amdgcn_mfma_f32_16x16x32_bf16(ap[0].v, bv, opv[0][nf], 0, 0, 0);
          opv[1][nf] = __builtin_amdgcn_mfma_f32_16x16x32_bf16(ap[1].v, bv, opv[1][nf], 0, 0, 0);
        }
      }
    }
    __syncthreads();  // drains vmcnt(0) for the stage issued above + lgkm + barrier
    buf ^= 1;
  }

#pragma unroll
  for (int qg = 0; qg < 2; qg++) {
    float s = lsum[qg];
    s += __shfl_xor(s, 16);
    s += __shfl_xor(s, 32);
    const float rinv = 1.f / s;
#pragma unroll
    for (int j = 0; j < 4; j++) {
      const float rj = __shfl(rinv, (khi << 2) + j);
      const size_t row = (size_t)(b * T_ + qw + qg * 16 + (khi << 2) + j) * ENC_C + h * HD_ + lr;
#pragma unroll
      for (int nf = 0; nf < 16; nf++) enc[row + (nf << 4)] = f2b(opv[qg][nf][j] * rj);
    }
  }
}

// ---------------- launcher ----------------
extern "C" void kernel_launch(void* const* d_in, const int* in_sizes, int n_in,
                              void* d_out, int out_size, void* d_ws, size_t ws_size,
                              hipStream_t stream) {
  const float* x = (const float*)d_in[0];
  const int* positions = (const int*)d_in[1];
  // d_in[2] attn_mask: causal tril by construction -> handled analytically
  const float* w_qkv = (const float*)d_in[3];
  const float* w_out = (const float*)d_in[4];
  float* out = (float*)d_out;

  char* ws = (char*)d_ws;
  u16* X16 = (u16*)(ws + 0);               // 32 MB : x bf16 (8192 x 2048)
  u16* WQT = (u16*)(ws + 33554432);        // 16 MB : w_qkv^T bf16 (4096 x 2048)
  u16* WOT = (u16*)(ws + 50331648);        //  8 MB : w_out^T bf16 (2048 x 2048)
  u16* QKV = (u16*)(ws + 58720256);        // 64 MB : qkv bf16 (8192 x 4096)
  u16* VT  = (u16*)(ws + 125829120);       // 16 MB : V^T bf16 (b,kv,HD,T)
  u16* ENC = X16;                          // alias (x bf16 dead after gemm1)

  cvt_f32_bf16<<<2048, 256, 0, stream>>>(x, X16, B_ * T_ * D_);
  {
    dim3 g(QKVC / 64, D_ / 64);
    transpose_cvt<<<g, 256, 0, stream>>>(w_qkv, WQT, D_, QKVC);
  }
  {
    dim3 g(D_ / 64, ENC_C / 64);
    transpose_cvt<<<g, 256, 0, stream>>>(w_out, WOT, ENC_C, D_);
  }
  gemm8p<false><<<(B_ * T_ / 256) * (QKVC / 256), 512, 0, stream>>>(X16, WQT, QKV,
                                                                    B_ * T_, QKVC, D_);
  rope_inplace<<<B_ * T_, 256, 0, stream>>>(QKV, positions);
  {
    dim3 g(T_ / 64, HD_ / 64, B_ * NKV_);
    vt_build<<<g, 256, 0, stream>>>(QKV, VT);
  }
  attn_kernel<<<256, 512, 0, stream>>>(QKV, VT, ENC);
  gemm8p<true><<<(B_ * T_ / 256) * (D_ / 256), 512, 0, stream>>>(ENC, WOT, out,
                                                                 B_ * T_, D_, ENC_C);
}